// Round 13
// baseline (1210.263 us; speedup 1.0000x reference)
//
#include <hip/hip_runtime.h>

typedef __attribute__((ext_vector_type(4))) float floatx4;
typedef __attribute__((ext_vector_type(8))) short short8;

// ---------- bf16 helpers (RNE) ----------
__device__ __forceinline__ float bf2f(unsigned short u) {
    union { unsigned int u; float f; } c; c.u = ((unsigned int)u) << 16; return c.f;
}
__device__ __forceinline__ unsigned short f2bf(float f) {
    union { float f; unsigned int u; } c; c.f = f;
    unsigned int r = c.u + 0x7FFFu + ((c.u >> 16) & 1u);
    return (unsigned short)(r >> 16);
}
__device__ __forceinline__ unsigned int pack2bf(float a, float b) {
    return (unsigned int)f2bf(a) | ((unsigned int)f2bf(b) << 16);
}

// ---------- async global->LDS, 16B per lane ----------
// NOTE: LDS dest is wave-uniform base + lane*16B. Every staging target below is
// arranged so a wave's lanes write offsets tid*16B within a contiguous panel.
__device__ __forceinline__ void load_lds16(const unsigned short* g, unsigned short* l) {
    __builtin_amdgcn_global_load_lds(
        (__attribute__((address_space(1))) void*)(g),
        (__attribute__((address_space(3))) void*)(l), 16, 0, 0);
}

// ---------- CSR build ----------
__global__ void k_hist(const int* __restrict__ dst, const int* __restrict__ et,
                       int* __restrict__ cnt4, int E) {
    int i = blockIdx.x * 256 + threadIdx.x;
    if (i < E) {
        atomicAdd(&cnt4[dst[i] * 4 + et[i]], 1);
    }
}

__global__ void k_scan_blk(const int* __restrict__ cnt4, int* __restrict__ row_ptr,
                           int* __restrict__ bsum, int N) {
    __shared__ int sm[256];
    int b = blockIdx.x, t = threadIdx.x, i = b * 256 + t;
    int v = 0;
    if (i < N) {
        const int4 q = ((const int4*)cnt4)[i];
        v = q.x + q.y + q.z + q.w;
    }
    sm[t] = v;
    __syncthreads();
    for (int off = 1; off < 256; off <<= 1) {
        int x = (t >= off) ? sm[t - off] : 0;
        __syncthreads();
        sm[t] += x;
        __syncthreads();
    }
    if (i < N) row_ptr[i] = sm[t] - v;
    if (t == 255) bsum[b] = sm[255];
}

__global__ void k_scan_top(int* __restrict__ bsum, int* __restrict__ boff,
                           int* __restrict__ row_ptr, int nblocks, int N) {
    __shared__ int sm[256];
    int t = threadIdx.x;
    int v = (t < nblocks) ? bsum[t] : 0;
    sm[t] = v;
    __syncthreads();
    for (int off = 1; off < 256; off <<= 1) {
        int x = (t >= off) ? sm[t - off] : 0;
        __syncthreads();
        sm[t] += x;
        __syncthreads();
    }
    if (t < nblocks) boff[t] = sm[t] - v;
    if (t == 255) row_ptr[N] = sm[255];
}

__global__ void k_scan_add(int* __restrict__ row_ptr, int* __restrict__ cursor,
                           const int* __restrict__ boff, int N) {
    int i = blockIdx.x * 256 + threadIdx.x;
    if (i < N) {
        int r = row_ptr[i] + boff[blockIdx.x];
        row_ptr[i] = r;
        cursor[i]  = r;
    }
}

__global__ void k_scatter(const int* __restrict__ src, const int* __restrict__ dst,
                          const int* __restrict__ et, int* __restrict__ cursor,
                          int* __restrict__ edge_pk, int E) {
    int i = blockIdx.x * 256 + threadIdx.x;
    if (i < E) {
        int p = atomicAdd(&cursor[dst[i]], 1);
        edge_pk[p] = src[i] | (et[i] << 16);   // src < 65536 for N=50000
    }
}

// ---------- init h (bf16) into AH[:,128:256] ----------
__global__ void k_init_h(const float* __restrict__ feat, unsigned short* __restrict__ AH, int N) {
    int i = blockIdx.x * 256 + threadIdx.x;
    if (i < N * 128) {
        int v = i >> 7, d = i & 127;
        AH[(size_t)v * 256 + 128 + d] = f2bf(feat[i]);
    }
}

// ---------- weight prep: hi/lo bf16 split, n-major [Nout][K] ----------
__global__ void k_prep_wcat(const float* __restrict__ W, unsigned short* __restrict__ hi,
                            unsigned short* __restrict__ lo) {
    int i = blockIdx.x * 256 + threadIdx.x;   // 4*128*128 = 65536
    if (i < 65536) {
        int t = i >> 14, o = (i >> 7) & 127, d = i & 127;
        float w = W[i];
        unsigned short h = f2bf(w);
        int idx = o * 512 + t * 128 + d;
        hi[idx] = h;
        lo[idx] = f2bf(w - bf2f(h));
    }
}

// r,z rows: Wrz[256][256], row j = [W_ih[j] | W_hh[j]]
__global__ void k_prep_wrz(const float* __restrict__ Wih, const float* __restrict__ Whh,
                           unsigned short* __restrict__ hi, unsigned short* __restrict__ lo) {
    int i = blockIdx.x * 256 + threadIdx.x;   // 256*256
    if (i < 256 * 256) {
        int j = i >> 8, k = i & 255;
        float w = (k < 128) ? Wih[j * 128 + k] : Whh[j * 128 + (k - 128)];
        unsigned short h = f2bf(w);
        hi[i] = h;
        lo[i] = f2bf(w - bf2f(h));
    }
}

// i_n rows: Win[128][128] = Wih rows 256..383 (a-half only)
// h_n rows: Whn[128][128] = Whh rows 256..383 (h-half only)
__global__ void k_prep_wnh(const float* __restrict__ Wih, const float* __restrict__ Whh,
                           unsigned short* __restrict__ in_hi, unsigned short* __restrict__ in_lo,
                           unsigned short* __restrict__ hn_hi, unsigned short* __restrict__ hn_lo) {
    int i = blockIdx.x * 256 + threadIdx.x;   // 128*128
    if (i < 128 * 128) {
        int c = i >> 7, k = i & 127;
        float wi = Wih[(256 + c) * 128 + k];
        float wh = Whh[(256 + c) * 128 + k];
        unsigned short hi1 = f2bf(wi);
        in_hi[i] = hi1;
        in_lo[i] = f2bf(wi - bf2f(hi1));
        unsigned short hi2 = f2bf(wh);
        hn_hi[i] = hi2;
        hn_lo[i] = f2bf(wh - bf2f(hi2));
    }
}

// ---------- per-step: aggregate h[src] by (dst, etype): S[v][t*128+d] ----------
// 16-deep clamped gather batches: ~97% of nodes (mean deg ~10) complete in ONE
// latency-exposed round. Clamped duplicate gathers hit L1 (same line). Per-bucket
// accumulation order identical to serial (bit-exact).
__global__ __launch_bounds__(256) void k_aggregate(
    const int* __restrict__ row_ptr, const int* __restrict__ edge_pk,
    const unsigned short* __restrict__ AH, unsigned short* __restrict__ S, int N)
{
    int wv = threadIdx.x >> 6;
    int lane = threadIdx.x & 63;
    int v = blockIdx.x * 4 + wv;
    if (v >= N) return;
    int beg = row_ptr[v], end = row_ptr[v + 1];
    float a0x = 0, a0y = 0, a1x = 0, a1y = 0, a2x = 0, a2y = 0, a3x = 0, a3y = 0;

    const unsigned short* hbase = AH + 128 + lane * 2;

#define ACC_EDGE(EP, HV)                                            \
    {                                                               \
        int t_ = (EP) >> 16;                                        \
        float x0_ = bf2f((unsigned short)((HV) & 0xFFFF));          \
        float x1_ = bf2f((unsigned short)((HV) >> 16));             \
        if (t_ == 0)      { a0x += x0_; a0y += x1_; }               \
        else if (t_ == 1) { a1x += x0_; a1y += x1_; }               \
        else if (t_ == 2) { a2x += x0_; a2y += x1_; }               \
        else              { a3x += x0_; a3y += x1_; }               \
    }

    for (int e = beg; e < end; e += 16) {
        int ep[16];
        unsigned int hv[16];
#pragma unroll
        for (int u = 0; u < 16; ++u) {
            int idx = e + u;
            if (idx > end - 1) idx = end - 1;
            ep[u] = edge_pk[idx];
        }
#pragma unroll
        for (int u = 0; u < 16; ++u)
            hv[u] = *(const unsigned int*)(hbase + (size_t)(ep[u] & 0xFFFF) * 256);
#pragma unroll
        for (int u = 0; u < 16; ++u) {
            if (e + u < end) ACC_EDGE(ep[u], hv[u]);
        }
    }
#undef ACC_EDGE

    unsigned int* Sp = (unsigned int*)&S[(size_t)v * 512];
    Sp[lane]       = pack2bf(a0x, a0y);
    Sp[64 + lane]  = pack2bf(a1x, a1y);
    Sp[128 + lane] = pack2bf(a2x, a2y);
    Sp[192 + lane] = pack2bf(a3x, a3y);
}

// ---------- etype GEMM: C[128,128] tile, K=512, BK=64 as 2x32 panels ----------
// Panels keep each global_load_lds wave-contiguous (lds off = panel + tid*8 elems).
// Per-acc MFMA order: k0-hi, k0-lo, k0+32-hi, k0+32-lo -> bit-exact vs BK=32.
__global__ __launch_bounds__(256) void k_gemm0(
    const unsigned short* __restrict__ A, int M,
    const unsigned short* __restrict__ Bhi, const unsigned short* __restrict__ Blo,
    unsigned short* __restrict__ outAH, const int* __restrict__ cnt4,
    const float* __restrict__ b_et)
{
    __shared__ __align__(16) unsigned short As[2][128 * 32];
    __shared__ __align__(16) unsigned short Bhs[2][128 * 32];
    __shared__ __align__(16) unsigned short Bls[2][128 * 32];
    const int tid  = threadIdx.x;
    const int lane = tid & 63;
    const int wv   = tid >> 6;
    const int wm   = (wv & 1) * 64;
    const int wn   = (wv >> 1) * 64;
    const int mBase = blockIdx.x * 128;
    const int srow = tid >> 2;
    const int sseg = (tid & 3) * 8;
    const int Ktot = 512;

    floatx4 acc[4][4];
#pragma unroll
    for (int i = 0; i < 4; ++i)
#pragma unroll
        for (int j = 0; j < 4; ++j) acc[i][j] = (floatx4){0.f, 0.f, 0.f, 0.f};

    int r0 = mBase + srow;      if (r0 >= M) r0 = M - 1;
    int r1 = mBase + srow + 64; if (r1 >= M) r1 = M - 1;

    for (int k0 = 0; k0 < Ktot; k0 += 64) {
        __syncthreads();
#pragma unroll
        for (int sub = 0; sub < 2; ++sub) {
            const int ko = k0 + sub * 32;
            load_lds16(A + (size_t)r0 * 512 + ko + sseg, &As[sub][srow * 32 + sseg]);
            load_lds16(A + (size_t)r1 * 512 + ko + sseg, &As[sub][(srow + 64) * 32 + sseg]);
            const unsigned short* bh = Bhi + (size_t)srow * Ktot + ko + sseg;
            load_lds16(bh,                     &Bhs[sub][srow * 32 + sseg]);
            load_lds16(bh + (size_t)64 * Ktot, &Bhs[sub][(srow + 64) * 32 + sseg]);
            const unsigned short* bl = Blo + (size_t)srow * Ktot + ko + sseg;
            load_lds16(bl,                     &Bls[sub][srow * 32 + sseg]);
            load_lds16(bl + (size_t)64 * Ktot, &Bls[sub][(srow + 64) * 32 + sseg]);
        }
        __syncthreads();
        const int kof = (lane >> 4) * 8;
        const int mr  = lane & 15;
#pragma unroll
        for (int p = 0; p < 2; ++p) {
            short8 af[4], bh[4], bl[4];
#pragma unroll
            for (int i = 0; i < 4; ++i) af[i] = *(const short8*)&As[p][(wm + i * 16 + mr) * 32 + kof];
#pragma unroll
            for (int j = 0; j < 4; ++j) bh[j] = *(const short8*)&Bhs[p][(wn + j * 16 + mr) * 32 + kof];
#pragma unroll
            for (int j = 0; j < 4; ++j) bl[j] = *(const short8*)&Bls[p][(wn + j * 16 + mr) * 32 + kof];
#pragma unroll
            for (int i = 0; i < 4; ++i)
#pragma unroll
                for (int j = 0; j < 4; ++j) {
                    acc[i][j] = __builtin_amdgcn_mfma_f32_16x16x32_bf16(af[i], bh[j], acc[i][j], 0, 0, 0);
                    acc[i][j] = __builtin_amdgcn_mfma_f32_16x16x32_bf16(af[i], bl[j], acc[i][j], 0, 0, 0);
                }
        }
    }

    const int mr4 = (lane >> 4) * 4;
    const int nc  = lane & 15;
#pragma unroll
    for (int i = 0; i < 4; ++i) {
#pragma unroll
        for (int r = 0; r < 4; ++r) {
            int row = mBase + wm + i * 16 + mr4 + r;
            if (row < M) {
                int cx = cnt4[row * 4 + 0], cy = cnt4[row * 4 + 1];
                int cz = cnt4[row * 4 + 2], cw = cnt4[row * 4 + 3];
#pragma unroll
                for (int j = 0; j < 4; ++j) {
                    int col = wn + j * 16 + nc;
                    float val = acc[i][j][r]
                        + (float)cx * b_et[col]       + (float)cy * b_et[128 + col]
                        + (float)cz * b_et[256 + col] + (float)cw * b_et[384 + col];
                    outAH[(size_t)row * 256 + col] = f2bf(val);
                }
            }
        }
    }
}

// ---------- gates GEMM, zero-block-eliminated K-split, BK=64 as 2x32 panels ----------
// grid (mblocks, 4): y=0,1 -> r,z cols (K=256); y=2 -> i_n (K=128, a-half);
// y=3 -> h_n (K=128, h-half). Bit-exact vs full-K version.
__global__ __launch_bounds__(256) void k_gemm1(
    const unsigned short* __restrict__ A, int M,
    const unsigned short* __restrict__ Wrz_hi, const unsigned short* __restrict__ Wrz_lo,
    const unsigned short* __restrict__ Win_hi, const unsigned short* __restrict__ Win_lo,
    const unsigned short* __restrict__ Whn_hi, const unsigned short* __restrict__ Whn_lo,
    _Float16* __restrict__ G)
{
    __shared__ __align__(16) unsigned short As[2][128 * 32];
    __shared__ __align__(16) unsigned short Bhs[2][128 * 32];
    __shared__ __align__(16) unsigned short Bls[2][128 * 32];
    const int tid  = threadIdx.x;
    const int lane = tid & 63;
    const int wv   = tid >> 6;
    const int wm   = (wv & 1) * 64;
    const int wn   = (wv >> 1) * 64;
    const int mBase = blockIdx.x * 128;
    const int y    = blockIdx.y;
    const int srow = tid >> 2;
    const int sseg = (tid & 3) * 8;

    const unsigned short* Bhi;
    const unsigned short* Blo;
    int Ktot, aOff, colBase;
    if (y < 2)      { Bhi = Wrz_hi + (size_t)y * 128 * 256; Blo = Wrz_lo + (size_t)y * 128 * 256;
                      Ktot = 256; aOff = 0;   colBase = y * 128; }
    else if (y == 2){ Bhi = Win_hi; Blo = Win_lo; Ktot = 128; aOff = 0;   colBase = 256; }
    else            { Bhi = Whn_hi; Blo = Whn_lo; Ktot = 128; aOff = 128; colBase = 384; }

    floatx4 acc[4][4];
#pragma unroll
    for (int i = 0; i < 4; ++i)
#pragma unroll
        for (int j = 0; j < 4; ++j) acc[i][j] = (floatx4){0.f, 0.f, 0.f, 0.f};

    int r0 = mBase + srow;      if (r0 >= M) r0 = M - 1;
    int r1 = mBase + srow + 64; if (r1 >= M) r1 = M - 1;

    for (int k0 = 0; k0 < Ktot; k0 += 64) {
        __syncthreads();
#pragma unroll
        for (int sub = 0; sub < 2; ++sub) {
            const int ko = k0 + sub * 32;
            load_lds16(A + (size_t)r0 * 256 + aOff + ko + sseg, &As[sub][srow * 32 + sseg]);
            load_lds16(A + (size_t)r1 * 256 + aOff + ko + sseg, &As[sub][(srow + 64) * 32 + sseg]);
            const unsigned short* bh = Bhi + (size_t)srow * Ktot + ko + sseg;
            load_lds16(bh,                     &Bhs[sub][srow * 32 + sseg]);
            load_lds16(bh + (size_t)64 * Ktot, &Bhs[sub][(srow + 64) * 32 + sseg]);
            const unsigned short* bl = Blo + (size_t)srow * Ktot + ko + sseg;
            load_lds16(bl,                     &Bls[sub][srow * 32 + sseg]);
            load_lds16(bl + (size_t)64 * Ktot, &Bls[sub][(srow + 64) * 32 + sseg]);
        }
        __syncthreads();
        const int kof = (lane >> 4) * 8;
        const int mr  = lane & 15;
#pragma unroll
        for (int p = 0; p < 2; ++p) {
            short8 af[4], bh[4], bl[4];
#pragma unroll
            for (int i = 0; i < 4; ++i) af[i] = *(const short8*)&As[p][(wm + i * 16 + mr) * 32 + kof];
#pragma unroll
            for (int j = 0; j < 4; ++j) bh[j] = *(const short8*)&Bhs[p][(wn + j * 16 + mr) * 32 + kof];
#pragma unroll
            for (int j = 0; j < 4; ++j) bl[j] = *(const short8*)&Bls[p][(wn + j * 16 + mr) * 32 + kof];
#pragma unroll
            for (int i = 0; i < 4; ++i)
#pragma unroll
                for (int j = 0; j < 4; ++j) {
                    acc[i][j] = __builtin_amdgcn_mfma_f32_16x16x32_bf16(af[i], bh[j], acc[i][j], 0, 0, 0);
                    acc[i][j] = __builtin_amdgcn_mfma_f32_16x16x32_bf16(af[i], bl[j], acc[i][j], 0, 0, 0);
                }
        }
    }

    const int mr4 = (lane >> 4) * 4;
    const int nc  = lane & 15;
#pragma unroll
    for (int i = 0; i < 4; ++i) {
#pragma unroll
        for (int r = 0; r < 4; ++r) {
            int row = mBase + wm + i * 16 + mr4 + r;
            if (row < M) {
#pragma unroll
                for (int j = 0; j < 4; ++j) {
                    int col = colBase + wn + j * 16 + nc;
                    G[(size_t)row * 512 + col] = (_Float16)acc[i][j][r];
                }
            }
        }
    }
}

// ---------- GRU elementwise (fp16 G, 2 dims/thread) ----------
__global__ void k_gru(const _Float16* __restrict__ G, unsigned short* __restrict__ AH,
                      const float* __restrict__ b_ih, const float* __restrict__ b_hh, int N) {
    int i = blockIdx.x * 256 + threadIdx.x;
    if (i >= N * 64) return;
    int v = i >> 6, j = i & 63;          // pair index (2 dims)
    const unsigned int* g32 = (const unsigned int*)(G + (size_t)v * 512);
    union U { unsigned int u; _Float16 h[2]; };
    U pr, pz, pn, ph;
    pr.u = g32[j];
    pz.u = g32[64 + j];
    pn.u = g32[128 + j];
    ph.u = g32[192 + j];
    unsigned int hv = *(const unsigned int*)&AH[(size_t)v * 256 + 128 + j * 2];
    float outs[2];
#pragma unroll
    for (int q = 0; q < 2; ++q) {
        int d = j * 2 + q;
        float pre_r = (float)pr.h[q] + b_ih[d]       + b_hh[d];
        float pre_z = (float)pz.h[q] + b_ih[128 + d] + b_hh[128 + d];
        float i_n   = (float)pn.h[q] + b_ih[256 + d];
        float h_n   = (float)ph.h[q] + b_hh[256 + d];
        float r = 1.f / (1.f + __expf(-pre_r));
        float z = 1.f / (1.f + __expf(-pre_z));
        float n = tanhf(i_n + r * h_n);
        float h = bf2f((unsigned short)(q == 0 ? (hv & 0xFFFF) : (hv >> 16)));
        outs[q] = (1.f - z) * n + z * h;
    }
    *(unsigned int*)&AH[(size_t)v * 256 + 128 + j * 2] = pack2bf(outs[0], outs[1]);
}

// ---------- readout stage 1: per-node classifier dot (no atomics) ----------
__global__ void k_dotv(const unsigned short* __restrict__ AH, const float* __restrict__ cls_w,
                       float* __restrict__ dotv, int N) {
    int v = blockIdx.x * 4 + (threadIdx.x >> 6);
    int lane = threadIdx.x & 63;
    if (v >= N) return;
    unsigned int hv = *(const unsigned int*)&AH[(size_t)v * 256 + 128 + lane * 2];
    float x = bf2f((unsigned short)(hv & 0xFFFF)) * cls_w[lane * 2]
            + bf2f((unsigned short)(hv >> 16))    * cls_w[lane * 2 + 1];
#pragma unroll
    for (int off = 32; off > 0; off >>= 1) x += __shfl_down(x, off);
    if (lane == 0) dotv[v] = x;
}

// ---------- readout stage 2: per-graph sum over sorted gids + sigmoid ----------
__global__ void k_gsum(const float* __restrict__ dotv, const int* __restrict__ gids,
                       const float* __restrict__ cls_b, float* __restrict__ out, int N) {
    int g = blockIdx.x;
    int t = threadIdx.x;   // 256
    int lo = 0, hi = N;
    while (lo < hi) { int m = (lo + hi) >> 1; if (gids[m] < g) lo = m + 1; else hi = m; }
    int s = lo;
    lo = 0; hi = N;
    while (lo < hi) { int m = (lo + hi) >> 1; if (gids[m] < g + 1) lo = m + 1; else hi = m; }
    int e = lo;
    float acc = 0.f;
    for (int v = s + t; v < e; v += 256) acc += dotv[v];
    __shared__ float red[256];
    red[t] = acc;
    __syncthreads();
    for (int off = 128; off > 0; off >>= 1) {
        if (t < off) red[t] += red[t + off];
        __syncthreads();
    }
    if (t == 0) out[g] = 1.f / (1.f + expf(-(red[0] + cls_b[0])));
}

// ---------- host ----------
extern "C" void kernel_launch(void* const* d_in, const int* in_sizes, int n_in,
                              void* d_out, int out_size, void* d_ws, size_t ws_size,
                              hipStream_t stream) {
    const float* features = (const float*)d_in[0];
    const int*   src      = (const int*)d_in[1];
    const int*   dst      = (const int*)d_in[2];
    const int*   etype    = (const int*)d_in[3];
    const int*   gids     = (const int*)d_in[4];
    const float* W_etype  = (const float*)d_in[5];
    const float* b_etype  = (const float*)d_in[6];
    const float* W_ih     = (const float*)d_in[7];
    const float* W_hh     = (const float*)d_in[8];
    const float* b_ih     = (const float*)d_in[9];
    const float* b_hh     = (const float*)d_in[10];
    const float* cls_w    = (const float*)d_in[11];
    const float* cls_b    = (const float*)d_in[12];
    const int N = in_sizes[0] / 128;
    const int E = in_sizes[1];
    float* out = (float*)d_out;

    char* ws = (char*)d_ws;
    size_t off = 0;
    auto alloc = [&](size_t bytes) -> void* {
        off = (off + 255) & ~(size_t)255;
        void* p = ws + off;
        off += bytes;
        return p;
    };
    unsigned short* AH    = (unsigned short*)alloc((size_t)N * 256 * 2); // [a | h] bf16
    unsigned short* S     = (unsigned short*)alloc((size_t)N * 512 * 2);
    _Float16*       G     = (_Float16*)alloc((size_t)N * 512 * 2);       // fp16 gates
    unsigned short* Wc_hi = (unsigned short*)alloc(128 * 512 * 2);
    unsigned short* Wc_lo = (unsigned short*)alloc(128 * 512 * 2);
    unsigned short* Wrz_hi = (unsigned short*)alloc(256 * 256 * 2);
    unsigned short* Wrz_lo = (unsigned short*)alloc(256 * 256 * 2);
    unsigned short* Win_hi = (unsigned short*)alloc(128 * 128 * 2);
    unsigned short* Win_lo = (unsigned short*)alloc(128 * 128 * 2);
    unsigned short* Whn_hi = (unsigned short*)alloc(128 * 128 * 2);
    unsigned short* Whn_lo = (unsigned short*)alloc(128 * 128 * 2);
    int* row_ptr = (int*)alloc((size_t)(N + 1) * 4);
    int* cursor  = (int*)alloc((size_t)N * 4);
    int* cnt4    = (int*)alloc((size_t)N * 16);
    int* edge_pk = (int*)alloc((size_t)E * 4);
    float* dotv  = (float*)alloc((size_t)N * 4);
    int* bsum    = (int*)alloc(256 * 4);
    int* boff    = (int*)alloc(256 * 4);
    (void)ws_size; (void)n_in;

    const int nscan = (N + 255) / 256;   // must be <= 256
    hipMemsetAsync(cnt4, 0, (size_t)N * 16, stream);
    k_hist<<<(E + 255) / 256, 256, 0, stream>>>(dst, etype, cnt4, E);
    k_scan_blk<<<nscan, 256, 0, stream>>>(cnt4, row_ptr, bsum, N);
    k_scan_top<<<1, 256, 0, stream>>>(bsum, boff, row_ptr, nscan, N);
    k_scan_add<<<nscan, 256, 0, stream>>>(row_ptr, cursor, boff, N);
    k_scatter<<<(E + 255) / 256, 256, 0, stream>>>(src, dst, etype, cursor, edge_pk, E);
    k_init_h<<<(N * 128 + 255) / 256, 256, 0, stream>>>(features, AH, N);
    k_prep_wcat<<<65536 / 256, 256, 0, stream>>>(W_etype, Wc_hi, Wc_lo);
    k_prep_wrz<<<(256 * 256) / 256, 256, 0, stream>>>(W_ih, W_hh, Wrz_hi, Wrz_lo);
    k_prep_wnh<<<(128 * 128) / 256, 256, 0, stream>>>(W_ih, W_hh, Win_hi, Win_lo, Whn_hi, Whn_lo);

    const int mblocks128 = (N + 127) / 128;
    for (int s = 0; s < 8; ++s) {
        k_aggregate<<<(N + 3) / 4, 256, 0, stream>>>(row_ptr, edge_pk, AH, S, N);
        k_gemm0<<<mblocks128, 256, 0, stream>>>(S, N, Wc_hi, Wc_lo, AH, cnt4, b_etype);
        dim3 g2(mblocks128, 4);
        k_gemm1<<<g2, 256, 0, stream>>>(AH, N, Wrz_hi, Wrz_lo, Win_hi, Win_lo, Whn_hi, Whn_lo, G);
        k_gru<<<(N * 64 + 255) / 256, 256, 0, stream>>>(G, AH, b_ih, b_hh, N);
    }
    k_dotv<<<(N + 3) / 4, 256, 0, stream>>>(AH, cls_w, dotv, N);
    k_gsum<<<out_size, 256, 0, stream>>>(dotv, gids, cls_b, out, N);
}

// Round 14
// 1094.748 us; speedup vs baseline: 1.1055x; 1.1055x over previous
//
#include <hip/hip_runtime.h>

typedef __attribute__((ext_vector_type(4))) float floatx4;
typedef __attribute__((ext_vector_type(8))) short short8;

// ---------- bf16 helpers (RNE) ----------
__device__ __forceinline__ float bf2f(unsigned short u) {
    union { unsigned int u; float f; } c; c.u = ((unsigned int)u) << 16; return c.f;
}
__device__ __forceinline__ unsigned short f2bf(float f) {
    union { float f; unsigned int u; } c; c.f = f;
    unsigned int r = c.u + 0x7FFFu + ((c.u >> 16) & 1u);
    return (unsigned short)(r >> 16);
}
__device__ __forceinline__ unsigned int pack2bf(float a, float b) {
    return (unsigned int)f2bf(a) | ((unsigned int)f2bf(b) << 16);
}

// ---------- async global->LDS, 16B per lane ----------
// NOTE: LDS dest is wave-uniform base + lane*16B. Every staging target below is
// arranged so a wave's lanes write offsets tid*16B within a contiguous panel.
__device__ __forceinline__ void load_lds16(const unsigned short* g, unsigned short* l) {
    __builtin_amdgcn_global_load_lds(
        (__attribute__((address_space(1))) void*)(g),
        (__attribute__((address_space(3))) void*)(l), 16, 0, 0);
}

// ---------- CSR build ----------
__global__ void k_hist(const int* __restrict__ dst, const int* __restrict__ et,
                       int* __restrict__ cnt4, int E) {
    int i = blockIdx.x * 256 + threadIdx.x;
    if (i < E) {
        atomicAdd(&cnt4[dst[i] * 4 + et[i]], 1);
    }
}

__global__ void k_scan_blk(const int* __restrict__ cnt4, int* __restrict__ row_ptr,
                           int* __restrict__ bsum, int N) {
    __shared__ int sm[256];
    int b = blockIdx.x, t = threadIdx.x, i = b * 256 + t;
    int v = 0;
    if (i < N) {
        const int4 q = ((const int4*)cnt4)[i];
        v = q.x + q.y + q.z + q.w;
    }
    sm[t] = v;
    __syncthreads();
    for (int off = 1; off < 256; off <<= 1) {
        int x = (t >= off) ? sm[t - off] : 0;
        __syncthreads();
        sm[t] += x;
        __syncthreads();
    }
    if (i < N) row_ptr[i] = sm[t] - v;
    if (t == 255) bsum[b] = sm[255];
}

__global__ void k_scan_top(int* __restrict__ bsum, int* __restrict__ boff,
                           int* __restrict__ row_ptr, int nblocks, int N) {
    __shared__ int sm[256];
    int t = threadIdx.x;
    int v = (t < nblocks) ? bsum[t] : 0;
    sm[t] = v;
    __syncthreads();
    for (int off = 1; off < 256; off <<= 1) {
        int x = (t >= off) ? sm[t - off] : 0;
        __syncthreads();
        sm[t] += x;
        __syncthreads();
    }
    if (t < nblocks) boff[t] = sm[t] - v;
    if (t == 255) row_ptr[N] = sm[255];
}

__global__ void k_scan_add(int* __restrict__ row_ptr, int* __restrict__ cursor,
                           const int* __restrict__ boff, int N) {
    int i = blockIdx.x * 256 + threadIdx.x;
    if (i < N) {
        int r = row_ptr[i] + boff[blockIdx.x];
        row_ptr[i] = r;
        cursor[i]  = r;
    }
}

__global__ void k_scatter(const int* __restrict__ src, const int* __restrict__ dst,
                          const int* __restrict__ et, int* __restrict__ cursor,
                          int* __restrict__ edge_pk, int E) {
    int i = blockIdx.x * 256 + threadIdx.x;
    if (i < E) {
        int p = atomicAdd(&cursor[dst[i]], 1);
        edge_pk[p] = src[i] | (et[i] << 16);   // src < 65536 for N=50000
    }
}

// ---------- init h (bf16) into AH[:,128:256] ----------
__global__ void k_init_h(const float* __restrict__ feat, unsigned short* __restrict__ AH, int N) {
    int i = blockIdx.x * 256 + threadIdx.x;
    if (i < N * 128) {
        int v = i >> 7, d = i & 127;
        AH[(size_t)v * 256 + 128 + d] = f2bf(feat[i]);
    }
}

// ---------- weight prep: hi/lo bf16 split, n-major [Nout][K] ----------
__global__ void k_prep_wcat(const float* __restrict__ W, unsigned short* __restrict__ hi,
                            unsigned short* __restrict__ lo) {
    int i = blockIdx.x * 256 + threadIdx.x;   // 4*128*128 = 65536
    if (i < 65536) {
        int t = i >> 14, o = (i >> 7) & 127, d = i & 127;
        float w = W[i];
        unsigned short h = f2bf(w);
        int idx = o * 512 + t * 128 + d;
        hi[idx] = h;
        lo[idx] = f2bf(w - bf2f(h));
    }
}

// r,z rows: Wrz[256][256], row j = [W_ih[j] | W_hh[j]]
__global__ void k_prep_wrz(const float* __restrict__ Wih, const float* __restrict__ Whh,
                           unsigned short* __restrict__ hi, unsigned short* __restrict__ lo) {
    int i = blockIdx.x * 256 + threadIdx.x;   // 256*256
    if (i < 256 * 256) {
        int j = i >> 8, k = i & 255;
        float w = (k < 128) ? Wih[j * 128 + k] : Whh[j * 128 + (k - 128)];
        unsigned short h = f2bf(w);
        hi[i] = h;
        lo[i] = f2bf(w - bf2f(h));
    }
}

// i_n rows: Win[128][128] = Wih rows 256..383 (a-half only)
// h_n rows: Whn[128][128] = Whh rows 256..383 (h-half only)
__global__ void k_prep_wnh(const float* __restrict__ Wih, const float* __restrict__ Whh,
                           unsigned short* __restrict__ in_hi, unsigned short* __restrict__ in_lo,
                           unsigned short* __restrict__ hn_hi, unsigned short* __restrict__ hn_lo) {
    int i = blockIdx.x * 256 + threadIdx.x;   // 128*128
    if (i < 128 * 128) {
        int c = i >> 7, k = i & 127;
        float wi = Wih[(256 + c) * 128 + k];
        float wh = Whh[(256 + c) * 128 + k];
        unsigned short hi1 = f2bf(wi);
        in_hi[i] = hi1;
        in_lo[i] = f2bf(wi - bf2f(hi1));
        unsigned short hi2 = f2bf(wh);
        hn_hi[i] = hi2;
        hn_lo[i] = f2bf(wh - bf2f(hi2));
    }
}

// ---------- per-step: aggregate h[src] by (dst, etype): S[v][t*128+d] ----------
// 8-deep clamped gather batches (measured optimum: 16-deep regressed — duplicate
// gathers + VGPR 52 made it issue-bound). Per-bucket order = serial (bit-exact).
__global__ __launch_bounds__(256) void k_aggregate(
    const int* __restrict__ row_ptr, const int* __restrict__ edge_pk,
    const unsigned short* __restrict__ AH, unsigned short* __restrict__ S, int N)
{
    int wv = threadIdx.x >> 6;
    int lane = threadIdx.x & 63;
    int v = blockIdx.x * 4 + wv;
    if (v >= N) return;
    int beg = row_ptr[v], end = row_ptr[v + 1];
    float a0x = 0, a0y = 0, a1x = 0, a1y = 0, a2x = 0, a2y = 0, a3x = 0, a3y = 0;

    const unsigned short* hbase = AH + 128 + lane * 2;

#define ACC_EDGE(EP, HV)                                            \
    {                                                               \
        int t_ = (EP) >> 16;                                        \
        float x0_ = bf2f((unsigned short)((HV) & 0xFFFF));          \
        float x1_ = bf2f((unsigned short)((HV) >> 16));             \
        if (t_ == 0)      { a0x += x0_; a0y += x1_; }               \
        else if (t_ == 1) { a1x += x0_; a1y += x1_; }               \
        else if (t_ == 2) { a2x += x0_; a2y += x1_; }               \
        else              { a3x += x0_; a3y += x1_; }               \
    }

    for (int e = beg; e < end; e += 8) {
        int ep[8];
        unsigned int hv[8];
#pragma unroll
        for (int u = 0; u < 8; ++u) {
            int idx = e + u;
            if (idx > end - 1) idx = end - 1;
            ep[u] = edge_pk[idx];
        }
#pragma unroll
        for (int u = 0; u < 8; ++u)
            hv[u] = *(const unsigned int*)(hbase + (size_t)(ep[u] & 0xFFFF) * 256);
#pragma unroll
        for (int u = 0; u < 8; ++u) {
            if (e + u < end) ACC_EDGE(ep[u], hv[u]);
        }
    }
#undef ACC_EDGE

    unsigned int* Sp = (unsigned int*)&S[(size_t)v * 512];
    Sp[lane]       = pack2bf(a0x, a0y);
    Sp[64 + lane]  = pack2bf(a1x, a1y);
    Sp[128 + lane] = pack2bf(a2x, a2y);
    Sp[192 + lane] = pack2bf(a3x, a3y);
}

// ---------- etype GEMM: C[128,128] tile, K=512, BK=64 as 2x32 panels ----------
// Panels keep each global_load_lds wave-contiguous (lds off = panel + tid*8 elems).
// Per-acc MFMA order: k0-hi, k0-lo, k0+32-hi, k0+32-lo -> bit-exact vs BK=32.
__global__ __launch_bounds__(256) void k_gemm0(
    const unsigned short* __restrict__ A, int M,
    const unsigned short* __restrict__ Bhi, const unsigned short* __restrict__ Blo,
    unsigned short* __restrict__ outAH, const int* __restrict__ cnt4,
    const float* __restrict__ b_et)
{
    __shared__ __align__(16) unsigned short As[2][128 * 32];
    __shared__ __align__(16) unsigned short Bhs[2][128 * 32];
    __shared__ __align__(16) unsigned short Bls[2][128 * 32];
    const int tid  = threadIdx.x;
    const int lane = tid & 63;
    const int wv   = tid >> 6;
    const int wm   = (wv & 1) * 64;
    const int wn   = (wv >> 1) * 64;
    const int mBase = blockIdx.x * 128;
    const int srow = tid >> 2;
    const int sseg = (tid & 3) * 8;
    const int Ktot = 512;

    floatx4 acc[4][4];
#pragma unroll
    for (int i = 0; i < 4; ++i)
#pragma unroll
        for (int j = 0; j < 4; ++j) acc[i][j] = (floatx4){0.f, 0.f, 0.f, 0.f};

    int r0 = mBase + srow;      if (r0 >= M) r0 = M - 1;
    int r1 = mBase + srow + 64; if (r1 >= M) r1 = M - 1;

    for (int k0 = 0; k0 < Ktot; k0 += 64) {
        __syncthreads();
#pragma unroll
        for (int sub = 0; sub < 2; ++sub) {
            const int ko = k0 + sub * 32;
            load_lds16(A + (size_t)r0 * 512 + ko + sseg, &As[sub][srow * 32 + sseg]);
            load_lds16(A + (size_t)r1 * 512 + ko + sseg, &As[sub][(srow + 64) * 32 + sseg]);
            const unsigned short* bh = Bhi + (size_t)srow * Ktot + ko + sseg;
            load_lds16(bh,                     &Bhs[sub][srow * 32 + sseg]);
            load_lds16(bh + (size_t)64 * Ktot, &Bhs[sub][(srow + 64) * 32 + sseg]);
            const unsigned short* bl = Blo + (size_t)srow * Ktot + ko + sseg;
            load_lds16(bl,                     &Bls[sub][srow * 32 + sseg]);
            load_lds16(bl + (size_t)64 * Ktot, &Bls[sub][(srow + 64) * 32 + sseg]);
        }
        __syncthreads();
        const int kof = (lane >> 4) * 8;
        const int mr  = lane & 15;
#pragma unroll
        for (int p = 0; p < 2; ++p) {
            short8 af[4], bh[4], bl[4];
#pragma unroll
            for (int i = 0; i < 4; ++i) af[i] = *(const short8*)&As[p][(wm + i * 16 + mr) * 32 + kof];
#pragma unroll
            for (int j = 0; j < 4; ++j) bh[j] = *(const short8*)&Bhs[p][(wn + j * 16 + mr) * 32 + kof];
#pragma unroll
            for (int j = 0; j < 4; ++j) bl[j] = *(const short8*)&Bls[p][(wn + j * 16 + mr) * 32 + kof];
#pragma unroll
            for (int i = 0; i < 4; ++i)
#pragma unroll
                for (int j = 0; j < 4; ++j) {
                    acc[i][j] = __builtin_amdgcn_mfma_f32_16x16x32_bf16(af[i], bh[j], acc[i][j], 0, 0, 0);
                    acc[i][j] = __builtin_amdgcn_mfma_f32_16x16x32_bf16(af[i], bl[j], acc[i][j], 0, 0, 0);
                }
        }
    }

    const int mr4 = (lane >> 4) * 4;
    const int nc  = lane & 15;
#pragma unroll
    for (int i = 0; i < 4; ++i) {
#pragma unroll
        for (int r = 0; r < 4; ++r) {
            int row = mBase + wm + i * 16 + mr4 + r;
            if (row < M) {
                int cx = cnt4[row * 4 + 0], cy = cnt4[row * 4 + 1];
                int cz = cnt4[row * 4 + 2], cw = cnt4[row * 4 + 3];
#pragma unroll
                for (int j = 0; j < 4; ++j) {
                    int col = wn + j * 16 + nc;
                    float val = acc[i][j][r]
                        + (float)cx * b_et[col]       + (float)cy * b_et[128 + col]
                        + (float)cz * b_et[256 + col] + (float)cw * b_et[384 + col];
                    outAH[(size_t)row * 256 + col] = f2bf(val);
                }
            }
        }
    }
}

// ---------- gates GEMM, zero-block-eliminated K-split, BK=64 as 2x32 panels ----------
// grid (mblocks, 4): y=0,1 -> r,z cols (K=256); y=2 -> i_n (K=128, a-half);
// y=3 -> h_n (K=128, h-half). Bit-exact vs full-K version.
__global__ __launch_bounds__(256) void k_gemm1(
    const unsigned short* __restrict__ A, int M,
    const unsigned short* __restrict__ Wrz_hi, const unsigned short* __restrict__ Wrz_lo,
    const unsigned short* __restrict__ Win_hi, const unsigned short* __restrict__ Win_lo,
    const unsigned short* __restrict__ Whn_hi, const unsigned short* __restrict__ Whn_lo,
    _Float16* __restrict__ G)
{
    __shared__ __align__(16) unsigned short As[2][128 * 32];
    __shared__ __align__(16) unsigned short Bhs[2][128 * 32];
    __shared__ __align__(16) unsigned short Bls[2][128 * 32];
    const int tid  = threadIdx.x;
    const int lane = tid & 63;
    const int wv   = tid >> 6;
    const int wm   = (wv & 1) * 64;
    const int wn   = (wv >> 1) * 64;
    const int mBase = blockIdx.x * 128;
    const int y    = blockIdx.y;
    const int srow = tid >> 2;
    const int sseg = (tid & 3) * 8;

    const unsigned short* Bhi;
    const unsigned short* Blo;
    int Ktot, aOff, colBase;
    if (y < 2)      { Bhi = Wrz_hi + (size_t)y * 128 * 256; Blo = Wrz_lo + (size_t)y * 128 * 256;
                      Ktot = 256; aOff = 0;   colBase = y * 128; }
    else if (y == 2){ Bhi = Win_hi; Blo = Win_lo; Ktot = 128; aOff = 0;   colBase = 256; }
    else            { Bhi = Whn_hi; Blo = Whn_lo; Ktot = 128; aOff = 128; colBase = 384; }

    floatx4 acc[4][4];
#pragma unroll
    for (int i = 0; i < 4; ++i)
#pragma unroll
        for (int j = 0; j < 4; ++j) acc[i][j] = (floatx4){0.f, 0.f, 0.f, 0.f};

    int r0 = mBase + srow;      if (r0 >= M) r0 = M - 1;
    int r1 = mBase + srow + 64; if (r1 >= M) r1 = M - 1;

    for (int k0 = 0; k0 < Ktot; k0 += 64) {
        __syncthreads();
#pragma unroll
        for (int sub = 0; sub < 2; ++sub) {
            const int ko = k0 + sub * 32;
            load_lds16(A + (size_t)r0 * 256 + aOff + ko + sseg, &As[sub][srow * 32 + sseg]);
            load_lds16(A + (size_t)r1 * 256 + aOff + ko + sseg, &As[sub][(srow + 64) * 32 + sseg]);
            const unsigned short* bh = Bhi + (size_t)srow * Ktot + ko + sseg;
            load_lds16(bh,                     &Bhs[sub][srow * 32 + sseg]);
            load_lds16(bh + (size_t)64 * Ktot, &Bhs[sub][(srow + 64) * 32 + sseg]);
            const unsigned short* bl = Blo + (size_t)srow * Ktot + ko + sseg;
            load_lds16(bl,                     &Bls[sub][srow * 32 + sseg]);
            load_lds16(bl + (size_t)64 * Ktot, &Bls[sub][(srow + 64) * 32 + sseg]);
        }
        __syncthreads();
        const int kof = (lane >> 4) * 8;
        const int mr  = lane & 15;
#pragma unroll
        for (int p = 0; p < 2; ++p) {
            short8 af[4], bh[4], bl[4];
#pragma unroll
            for (int i = 0; i < 4; ++i) af[i] = *(const short8*)&As[p][(wm + i * 16 + mr) * 32 + kof];
#pragma unroll
            for (int j = 0; j < 4; ++j) bh[j] = *(const short8*)&Bhs[p][(wn + j * 16 + mr) * 32 + kof];
#pragma unroll
            for (int j = 0; j < 4; ++j) bl[j] = *(const short8*)&Bls[p][(wn + j * 16 + mr) * 32 + kof];
#pragma unroll
            for (int i = 0; i < 4; ++i)
#pragma unroll
                for (int j = 0; j < 4; ++j) {
                    acc[i][j] = __builtin_amdgcn_mfma_f32_16x16x32_bf16(af[i], bh[j], acc[i][j], 0, 0, 0);
                    acc[i][j] = __builtin_amdgcn_mfma_f32_16x16x32_bf16(af[i], bl[j], acc[i][j], 0, 0, 0);
                }
        }
    }

    const int mr4 = (lane >> 4) * 4;
    const int nc  = lane & 15;
#pragma unroll
    for (int i = 0; i < 4; ++i) {
#pragma unroll
        for (int r = 0; r < 4; ++r) {
            int row = mBase + wm + i * 16 + mr4 + r;
            if (row < M) {
#pragma unroll
                for (int j = 0; j < 4; ++j) {
                    int col = colBase + wn + j * 16 + nc;
                    G[(size_t)row * 512 + col] = (_Float16)acc[i][j][r];
                }
            }
        }
    }
}

// ---------- GRU elementwise (fp16 G, 2 dims/thread) ----------
__global__ void k_gru(const _Float16* __restrict__ G, unsigned short* __restrict__ AH,
                      const float* __restrict__ b_ih, const float* __restrict__ b_hh, int N) {
    int i = blockIdx.x * 256 + threadIdx.x;
    if (i >= N * 64) return;
    int v = i >> 6, j = i & 63;          // pair index (2 dims)
    const unsigned int* g32 = (const unsigned int*)(G + (size_t)v * 512);
    union U { unsigned int u; _Float16 h[2]; };
    U pr, pz, pn, ph;
    pr.u = g32[j];
    pz.u = g32[64 + j];
    pn.u = g32[128 + j];
    ph.u = g32[192 + j];
    unsigned int hv = *(const unsigned int*)&AH[(size_t)v * 256 + 128 + j * 2];
    float outs[2];
#pragma unroll
    for (int q = 0; q < 2; ++q) {
        int d = j * 2 + q;
        float pre_r = (float)pr.h[q] + b_ih[d]       + b_hh[d];
        float pre_z = (float)pz.h[q] + b_ih[128 + d] + b_hh[128 + d];
        float i_n   = (float)pn.h[q] + b_ih[256 + d];
        float h_n   = (float)ph.h[q] + b_hh[256 + d];
        float r = 1.f / (1.f + __expf(-pre_r));
        float z = 1.f / (1.f + __expf(-pre_z));
        float n = tanhf(i_n + r * h_n);
        float h = bf2f((unsigned short)(q == 0 ? (hv & 0xFFFF) : (hv >> 16)));
        outs[q] = (1.f - z) * n + z * h;
    }
    *(unsigned int*)&AH[(size_t)v * 256 + 128 + j * 2] = pack2bf(outs[0], outs[1]);
}

// ---------- readout stage 1: per-node classifier dot (no atomics) ----------
__global__ void k_dotv(const unsigned short* __restrict__ AH, const float* __restrict__ cls_w,
                       float* __restrict__ dotv, int N) {
    int v = blockIdx.x * 4 + (threadIdx.x >> 6);
    int lane = threadIdx.x & 63;
    if (v >= N) return;
    unsigned int hv = *(const unsigned int*)&AH[(size_t)v * 256 + 128 + lane * 2];
    float x = bf2f((unsigned short)(hv & 0xFFFF)) * cls_w[lane * 2]
            + bf2f((unsigned short)(hv >> 16))    * cls_w[lane * 2 + 1];
#pragma unroll
    for (int off = 32; off > 0; off >>= 1) x += __shfl_down(x, off);
    if (lane == 0) dotv[v] = x;
}

// ---------- readout stage 2: per-graph sum over sorted gids + sigmoid ----------
__global__ void k_gsum(const float* __restrict__ dotv, const int* __restrict__ gids,
                       const float* __restrict__ cls_b, float* __restrict__ out, int N) {
    int g = blockIdx.x;
    int t = threadIdx.x;   // 256
    int lo = 0, hi = N;
    while (lo < hi) { int m = (lo + hi) >> 1; if (gids[m] < g) lo = m + 1; else hi = m; }
    int s = lo;
    lo = 0; hi = N;
    while (lo < hi) { int m = (lo + hi) >> 1; if (gids[m] < g + 1) lo = m + 1; else hi = m; }
    int e = lo;
    float acc = 0.f;
    for (int v = s + t; v < e; v += 256) acc += dotv[v];
    __shared__ float red[256];
    red[t] = acc;
    __syncthreads();
    for (int off = 128; off > 0; off >>= 1) {
        if (t < off) red[t] += red[t + off];
        __syncthreads();
    }
    if (t == 0) out[g] = 1.f / (1.f + expf(-(red[0] + cls_b[0])));
}

// ---------- host ----------
extern "C" void kernel_launch(void* const* d_in, const int* in_sizes, int n_in,
                              void* d_out, int out_size, void* d_ws, size_t ws_size,
                              hipStream_t stream) {
    const float* features = (const float*)d_in[0];
    const int*   src      = (const int*)d_in[1];
    const int*   dst      = (const int*)d_in[2];
    const int*   etype    = (const int*)d_in[3];
    const int*   gids     = (const int*)d_in[4];
    const float* W_etype  = (const float*)d_in[5];
    const float* b_etype  = (const float*)d_in[6];
    const float* W_ih     = (const float*)d_in[7];
    const float* W_hh     = (const float*)d_in[8];
    const float* b_ih     = (const float*)d_in[9];
    const float* b_hh     = (const float*)d_in[10];
    const float* cls_w    = (const float*)d_in[11];
    const float* cls_b    = (const float*)d_in[12];
    const int N = in_sizes[0] / 128;
    const int E = in_sizes[1];
    float* out = (float*)d_out;

    char* ws = (char*)d_ws;
    size_t off = 0;
    auto alloc = [&](size_t bytes) -> void* {
        off = (off + 255) & ~(size_t)255;
        void* p = ws + off;
        off += bytes;
        return p;
    };
    unsigned short* AH    = (unsigned short*)alloc((size_t)N * 256 * 2); // [a | h] bf16
    unsigned short* S     = (unsigned short*)alloc((size_t)N * 512 * 2);
    _Float16*       G     = (_Float16*)alloc((size_t)N * 512 * 2);       // fp16 gates
    unsigned short* Wc_hi = (unsigned short*)alloc(128 * 512 * 2);
    unsigned short* Wc_lo = (unsigned short*)alloc(128 * 512 * 2);
    unsigned short* Wrz_hi = (unsigned short*)alloc(256 * 256 * 2);
    unsigned short* Wrz_lo = (unsigned short*)alloc(256 * 256 * 2);
    unsigned short* Win_hi = (unsigned short*)alloc(128 * 128 * 2);
    unsigned short* Win_lo = (unsigned short*)alloc(128 * 128 * 2);
    unsigned short* Whn_hi = (unsigned short*)alloc(128 * 128 * 2);
    unsigned short* Whn_lo = (unsigned short*)alloc(128 * 128 * 2);
    int* row_ptr = (int*)alloc((size_t)(N + 1) * 4);
    int* cursor  = (int*)alloc((size_t)N * 4);
    int* cnt4    = (int*)alloc((size_t)N * 16);
    int* edge_pk = (int*)alloc((size_t)E * 4);
    float* dotv  = (float*)alloc((size_t)N * 4);
    int* bsum    = (int*)alloc(256 * 4);
    int* boff    = (int*)alloc(256 * 4);
    (void)ws_size; (void)n_in;

    const int nscan = (N + 255) / 256;   // must be <= 256
    hipMemsetAsync(cnt4, 0, (size_t)N * 16, stream);
    k_hist<<<(E + 255) / 256, 256, 0, stream>>>(dst, etype, cnt4, E);
    k_scan_blk<<<nscan, 256, 0, stream>>>(cnt4, row_ptr, bsum, N);
    k_scan_top<<<1, 256, 0, stream>>>(bsum, boff, row_ptr, nscan, N);
    k_scan_add<<<nscan, 256, 0, stream>>>(row_ptr, cursor, boff, N);
    k_scatter<<<(E + 255) / 256, 256, 0, stream>>>(src, dst, etype, cursor, edge_pk, E);
    k_init_h<<<(N * 128 + 255) / 256, 256, 0, stream>>>(features, AH, N);
    k_prep_wcat<<<65536 / 256, 256, 0, stream>>>(W_etype, Wc_hi, Wc_lo);
    k_prep_wrz<<<(256 * 256) / 256, 256, 0, stream>>>(W_ih, W_hh, Wrz_hi, Wrz_lo);
    k_prep_wnh<<<(128 * 128) / 256, 256, 0, stream>>>(W_ih, W_hh, Win_hi, Win_lo, Whn_hi, Whn_lo);

    const int mblocks128 = (N + 127) / 128;
    for (int s = 0; s < 8; ++s) {
        k_aggregate<<<(N + 3) / 4, 256, 0, stream>>>(row_ptr, edge_pk, AH, S, N);
        k_gemm0<<<mblocks128, 256, 0, stream>>>(S, N, Wc_hi, Wc_lo, AH, cnt4, b_etype);
        dim3 g2(mblocks128, 4);
        k_gemm1<<<g2, 256, 0, stream>>>(AH, N, Wrz_hi, Wrz_lo, Win_hi, Win_lo, Whn_hi, Whn_lo, G);
        k_gru<<<(N * 64 + 255) / 256, 256, 0, stream>>>(G, AH, b_ih, b_hh, N);
    }
    k_dotv<<<(N + 3) / 4, 256, 0, stream>>>(AH, cls_w, dotv, N);
    k_gsum<<<out_size, 256, 0, stream>>>(dotv, gids, cls_b, out, N);
}